// Round 12
// baseline (591.330 us; speedup 1.0000x reference)
//
#include <hip/hip_runtime.h>
#include <stdint.h>

typedef unsigned short u16;
typedef short s16x8 __attribute__((ext_vector_type(8)));
typedef u16   u16x8 __attribute__((ext_vector_type(8)));
typedef float f32x4 __attribute__((ext_vector_type(4)));
typedef float f32x16 __attribute__((ext_vector_type(16)));

#define QSCALE 0.180336880111169f  /* 0.125 * log2(e) */

__device__ __forceinline__ u16 f2bf(float f) {
  union { float f; uint32_t u; } v; v.f = f;
  uint32_t r = (v.u + 0x7fffu + ((v.u >> 16) & 1u)) >> 16;
  return (u16)r;
}
__device__ __forceinline__ float bf2f(u16 x) {
  union { uint32_t u; float f; } v; v.u = (uint32_t)x << 16;
  return v.f;
}

__device__ __forceinline__ f32x4 mfma16(s16x8 a, s16x8 b, f32x4 c) {
  return __builtin_amdgcn_mfma_f32_16x16x32_bf16(a, b, c, 0, 0, 0);
}
__device__ __forceinline__ f32x16 mfma32(s16x8 a, s16x8 b, f32x16 c) {
  return __builtin_amdgcn_mfma_f32_32x32x16_bf16(a, b, c, 0, 0, 0);
}

__device__ __forceinline__ void gload16(const void* g, void* l) {
  __builtin_amdgcn_global_load_lds(
      (const __attribute__((address_space(1))) void*)g,
      (__attribute__((address_space(3))) void*)l, 16, 0, 0);
}

// read 8 contiguous bf16 from a [*][64]-u16 LDS tile with (row&7)<<4 XOR swizzle
__device__ __forceinline__ s16x8 ldsr(const u16* base, int row, int colb) {
  return *(const s16x8*)((const char*)base + row * 128 + (colb ^ ((row & 7) << 4)));
}

// pack two f32 -> bf16x2 word (lo = first)
__device__ __forceinline__ uint32_t cvtpk(float lo, float hi) {
  uint32_t r;
  asm("v_cvt_pk_bf16_f32 %0, %1, %2" : "=v"(r) : "v"(lo), "v"(hi));
  return r;
}
// v_permlane32_swap: a'[l<32]=a, a'[l>=32]=b[l-32]; b'[l<32]=a[l+32], b'[l>=32]=b
__device__ __forceinline__ void hswap(uint32_t& a, uint32_t& b) {
  asm("v_permlane32_swap_b32 %0, %1" : "+v"(a), "+v"(b));
}
__device__ __forceinline__ float cross_sum(float v) {
  float t = v, u = v;
  asm("v_permlane32_swap_b32 %0, %1" : "+v"(t), "+v"(u));
  return t + u;
}

// ------ kernel 1: convert x/ctx + weights to bf16, write attn_map=1 ----------
__global__ void k_convert(const float* __restrict__ x, const float* __restrict__ ctx,
                          const float* __restrict__ wq, const float* __restrict__ wkv,
                          const float* __restrict__ wp,
                          u16* __restrict__ xb, u16* __restrict__ cb,
                          u16* __restrict__ wqT, u16* __restrict__ wkvT,
                          u16* __restrict__ wpT, float* __restrict__ amap) {
  int tid = blockIdx.x * 256 + threadIdx.x;
  if (tid < 2097152) {            // x (4.2M) + ctx (4.2M), 4 floats each
    const float* src; u16* dst; int off;
    if (tid < 1048576) { src = x;   dst = xb; off = tid * 4; }
    else               { src = ctx; dst = cb; off = (tid - 1048576) * 4; }
    f32x4 v = *(const f32x4*)(src + off);
    u16* d = dst + off;
    d[0] = f2bf(v.x); d[1] = f2bf(v.y); d[2] = f2bf(v.z); d[3] = f2bf(v.w);
    if (tid < 16384) amap[tid] = 1.0f;   // sum_k softmax == 1 exactly
  } else {                        // weights: 262144 elems, transpose to [N][K]
    int t4 = (tid - 2097152) * 4;
#pragma unroll
    for (int j = 0; j < 4; j++) {
      int t = t4 + j;
      if (t < 65536) {
        int k = t >> 8, n = t & 255;
        wqT[n * 256 + k] = f2bf(wq[t]);
      } else if (t < 196608) {
        int t2 = t - 65536;
        int k = t2 >> 9, n = t2 & 511;
        wkvT[n * 256 + k] = f2bf(wkv[t2]);
      } else {
        int t2 = t - 196608;
        int k = t2 >> 8, n = t2 & 255;
        wpT[n * 256 + k] = f2bf(wp[t2]);
      }
    }
  }
}

// ---------------- kernel 2/3/6: MFMA GEMM  C[M,N] = A[M,256] @ Bt[N,256]^T ---
// EPI 0: q-proj (scale, scatter [B,H,L,hd]) ; EPI 1: kv-proj (k->[B,H,Lc,hd],
// v->tiled V^T [bh][kv/64][hd][64]) ; EPI 2: out-proj (+bias +x, fp32)
template<int EPI>
__global__ __launch_bounds__(256, 2) void k_gemm(
    const u16* __restrict__ A, const u16* __restrict__ Bt,
    const float* __restrict__ bias, const float* __restrict__ xres,
    u16* __restrict__ o16a, u16* __restrict__ o16b, float* __restrict__ o32) {
  __shared__ u16 Als[2][128 * 64];
  __shared__ u16 Bls[2][64 * 64];
  const int m0 = blockIdx.x * 128;
  const int n0 = blockIdx.y * 64;
  const int tid = threadIdx.x, w = tid >> 6, l = tid & 63;
  const int lr = l & 15, lg = l >> 4;
  const int wm = (w >> 1) * 64, wn = (w & 1) * 32;

  auto stage = [&](int buf, int k0) {
    const char* sa = (const char*)A;
#pragma unroll
    for (int i = 0; i < 4; i++) {
      int dbase = (w * 4 + i) * 1024;
      int d = dbase + l * 16;
      int row = d >> 7, colb = d & 127;
      gload16(sa + (size_t)(m0 + row) * 512 + k0 * 2 + (colb ^ ((row & 7) << 4)),
              (char*)Als[buf] + dbase);
    }
    const char* sb = (const char*)Bt;
#pragma unroll
    for (int i = 0; i < 2; i++) {
      int dbase = (w * 2 + i) * 1024;
      int d = dbase + l * 16;
      int row = d >> 7, colb = d & 127;
      gload16(sb + (size_t)(n0 + row) * 512 + k0 * 2 + (colb ^ ((row & 7) << 4)),
              (char*)Bls[buf] + dbase);
    }
  };

  f32x4 acc[4][2];
#pragma unroll
  for (int i = 0; i < 4; i++)
#pragma unroll
    for (int j = 0; j < 2; j++) acc[i][j] = (f32x4){0.f, 0.f, 0.f, 0.f};

  stage(0, 0);
  __syncthreads();
  int cur = 0;
  for (int ks = 0; ks < 4; ks++) {           // K = 256, BK = 64
    if (ks < 3) stage(cur ^ 1, (ks + 1) * 64);
    s16x8 a[4][2], b[2][2];
#pragma unroll
    for (int mt = 0; mt < 4; mt++)
#pragma unroll
      for (int kf = 0; kf < 2; kf++)
        a[mt][kf] = ldsr(Als[cur], wm + mt * 16 + lr, lg * 16 + kf * 64);
#pragma unroll
    for (int nt = 0; nt < 2; nt++)
#pragma unroll
      for (int kf = 0; kf < 2; kf++)
        b[nt][kf] = ldsr(Bls[cur], wn + nt * 16 + lr, lg * 16 + kf * 64);
#pragma unroll
    for (int mt = 0; mt < 4; mt++)
#pragma unroll
      for (int nt = 0; nt < 2; nt++) {
        acc[mt][nt] = mfma16(a[mt][0], b[nt][0], acc[mt][nt]);
        acc[mt][nt] = mfma16(a[mt][1], b[nt][1], acc[mt][nt]);
      }
    __syncthreads();
    cur ^= 1;
  }

#pragma unroll
  for (int mt = 0; mt < 4; mt++)
#pragma unroll
    for (int nt = 0; nt < 2; nt++)
#pragma unroll
      for (int r = 0; r < 4; r++) {
        int gm = m0 + wm + mt * 16 + lg * 4 + r;
        int gn = n0 + wn + nt * 16 + lr;
        float val = acc[mt][nt][r] + bias[gn];
        if constexpr (EPI == 0) {
          int b_ = gm >> 12, ql = gm & 4095, h = gn >> 6, dd = gn & 63;
          o16a[(((size_t)(b_ * 4 + h) * 4096 + ql) << 6) + dd] = f2bf(val * QSCALE);
        } else if constexpr (EPI == 1) {
          int b_ = gm >> 12, ql = gm & 4095;
          int s = gn >> 8, inner = gn & 255, h = inner >> 6, dd = inner & 63;
          if (s) {  // V^T tiled: [bh][ql/64][dd][ql%64]
            size_t addr = (((size_t)(b_ * 4 + h) * 64 + (ql >> 6)) * 64 + dd) * 64 + (ql & 63);
            o16b[addr] = f2bf(val);
          } else {  // K: [bh][kv][hd]
            size_t addr = (((size_t)(b_ * 4 + h) * 4096 + ql) << 6) + dd;
            o16a[addr] = f2bf(val);
          }
        } else {
          size_t idx = (size_t)gm * 256 + gn;
          o32[idx] = val + xres[idx];
        }
      }
}

// ---------------- kernel 4: flash attention (R9 geometry, 3-way kv ranges) ---
// Swapped-QK 32x32 MFMA, no-max softmax (S_log2 bounded ~[-1,1]; constant
// cancels). 1536 blocks x 4 waves, launch_bounds(256,3): reg cap 170 >= ~160
// needed (96 arch + 64 acc) -> NO spill, 3 blk/CU, 12 waves/CU. Block =
// (bh, 128-q tile, kv range rng: tiles {0-20,21-41,42-63}). Wave geometry =
// R9: qq=w&1 64-q half, kvh=(w>>1)&1 32-kv half -> 8 b128 reads feed 16
// MFMAs. Partials additive: in-block kvh fold via dead-staging LDS, bf16
// partial O/lsum to global (3-way combined by k_reduce).
__global__ __launch_bounds__(256, 3) void k_flash(
    const u16* __restrict__ qb, const u16* __restrict__ kb,
    const u16* __restrict__ vtb, u16* __restrict__ pO01, u16* __restrict__ pO2,
    u16* __restrict__ pL) {
  __shared__ char smem[33792];
  u16* kls0 = (u16*)(smem);
  u16* kls1 = (u16*)(smem + 8192);
  u16* vls0 = (u16*)(smem + 16384);
  u16* vls1 = (u16*)(smem + 24576);
  float* comb = (float*)smem;               // overlays staging after loop
  const int id = blockIdx.y * 32 + blockIdx.x;      // 1536 blocks
  const int sw = (id & 7) * 192 + (id >> 3);        // XCD chunking (bijective)
  const int bh = sw / 96;                           // 2 bh per XCD chunk
  const int rem = sw - bh * 96;
  const int q0 = (rem / 3) * 128;
  const int rng = rem - (rem / 3) * 3;              // kv range 0..2
  const int t0 = rng * 21;
  const int nt = (rng == 2) ? 22 : 21;
  const int tid = threadIdx.x, w = tid >> 6, l = tid & 63;
  const int lr32 = l & 31, hi = l >> 5;
  const int qq = w & 1, kvh = (w >> 1) & 1;
  const char* kbase  = (const char*)(kb + (size_t)bh * 262144);
  const char* vtbase = (const char*)(vtb + (size_t)bh * 262144);

  // Q B-fragments, two qsets: qA: q = q0 + 64*qq + lr32 ; qB: +32
  s16x8 qfA[4], qfB[4];
  {
    const u16* qp = qb + ((size_t)bh * 4096 + q0 + qq * 64 + lr32) * 64 + hi * 8;
#pragma unroll
    for (int mm = 0; mm < 4; mm++) {
      qfA[mm] = *(const s16x8*)(qp + mm * 16);
      qfB[mm] = *(const s16x8*)(qp + 2048 + mm * 16);
    }
  }

  // stage K+V tile t (two contiguous 8KB tiles); 4 waves cover both
  auto stage = [&](u16* kbuf, u16* vbuf, int t) {
    const char* ks = kbase  + (size_t)t * 8192;
    const char* vs = vtbase + (size_t)t * 8192;
#pragma unroll
    for (int i = 0; i < 2; i++) {
      int d = w * 2048 + i * 1024 + l * 16;
      int row = d >> 7, colb = d & 127;
      int so = row * 128 + (colb ^ ((row & 7) << 4));
      gload16(ks + so, (char*)kbuf + d);
      gload16(vs + so, (char*)vbuf + d);
    }
  };

  f32x16 oA0, oA1, oB0, oB1;
  float lsA = 0.f, lsB = 0.f;
#pragma unroll
  for (int r = 0; r < 16; r++) { oA0[r] = 0.f; oA1[r] = 0.f; oB0[r] = 0.f; oB1[r] = 0.f; }

  auto compute = [&](const u16* kc, const u16* vc) {
    // K fragments for this wave's 32-kv half (4 reads, feed 8 QK MFMAs)
    s16x8 kf[4];
#pragma unroll
    for (int mm = 0; mm < 4; mm++)
      kf[mm] = ldsr(kc, kvh * 32 + lr32, mm * 32 + 16 * hi);
    f32x16 sA, sB;
#pragma unroll
    for (int r = 0; r < 16; r++) { sA[r] = 0.f; sB[r] = 0.f; }
    __builtin_amdgcn_s_setprio(1);
#pragma unroll
    for (int mm = 0; mm < 4; mm++) {
      sA = mfma32(kf[mm], qfA[mm], sA);
      sB = mfma32(kf[mm], qfB[mm], sB);
    }
    __builtin_amdgcn_s_setprio(0);
    // P = exp2(S); per-lane lsum
#pragma unroll
    for (int r = 0; r < 16; r++) {
      sA[r] = __builtin_amdgcn_exp2f(sA[r]);
      sB[r] = __builtin_amdgcn_exp2f(sB[r]);
    }
    float aA = 0.f, aB = 0.f;
#pragma unroll
    for (int r = 0; r < 16; r++) { aA += sA[r]; aB += sB[r]; }
    lsA += aA; lsB += aB;
    // V fragments (4 reads, feed 8 PV MFMAs across both qsets)
    s16x8 vf[2][2];
#pragma unroll
    for (int ks2 = 0; ks2 < 2; ks2++) {
      int vcol = kvh * 64 + 32 * ks2 + 16 * hi;
      vf[ks2][0] = ldsr(vc, lr32,      vcol);
      vf[ks2][1] = ldsr(vc, 32 + lr32, vcol);
    }
#pragma unroll
    for (int ks2 = 0; ks2 < 2; ks2++) {
      uint32_t A0 = cvtpk(sA[8 * ks2 + 0], sA[8 * ks2 + 1]);
      uint32_t A1 = cvtpk(sA[8 * ks2 + 2], sA[8 * ks2 + 3]);
      uint32_t B0 = cvtpk(sA[8 * ks2 + 4], sA[8 * ks2 + 5]);
      uint32_t B1 = cvtpk(sA[8 * ks2 + 6], sA[8 * ks2 + 7]);
      hswap(A0, B0);
      hswap(A1, B1);
      union { uint32_t wv[4]; s16x8 h; } pa;
      pa.wv[0] = A0; pa.wv[1] = A1; pa.wv[2] = B0; pa.wv[3] = B1;
      uint32_t C0 = cvtpk(sB[8 * ks2 + 0], sB[8 * ks2 + 1]);
      uint32_t C1 = cvtpk(sB[8 * ks2 + 2], sB[8 * ks2 + 3]);
      uint32_t D0 = cvtpk(sB[8 * ks2 + 4], sB[8 * ks2 + 5]);
      uint32_t D1 = cvtpk(sB[8 * ks2 + 6], sB[8 * ks2 + 7]);
      hswap(C0, D0);
      hswap(C1, D1);
      union { uint32_t wv[4]; s16x8 h; } pb;
      pb.wv[0] = C0; pb.wv[1] = C1; pb.wv[2] = D0; pb.wv[3] = D1;
      __builtin_amdgcn_s_setprio(1);
      oA0 = mfma32(pa.h, vf[ks2][0], oA0);
      oA1 = mfma32(pa.h, vf[ks2][1], oA1);
      oB0 = mfma32(pb.h, vf[ks2][0], oB0);
      oB1 = mfma32(pb.h, vf[ks2][1], oB1);
      __builtin_amdgcn_s_setprio(0);
    }
  };

  stage(kls0, vls0, t0);
  int i = 0;
  while (true) {
    asm volatile("s_waitcnt vmcnt(0)" ::: "memory");
    __builtin_amdgcn_s_barrier();
    asm volatile("" ::: "memory");
    if (i + 1 < nt) stage(kls1, vls1, t0 + i + 1);
    compute(kls0, vls0);
    if (++i == nt) break;
    asm volatile("s_waitcnt vmcnt(0)" ::: "memory");
    __builtin_amdgcn_s_barrier();
    asm volatile("" ::: "memory");
    if (i + 1 < nt) stage(kls0, vls0, t0 + i + 1);
    compute(kls1, vls1);
    if (++i == nt) break;
  }

  // ---- fold wave-kvh (additive partials), write bf16 partials -------------
  float ltA = cross_sum(lsA);   // range kv sum for q = q0+64qq+lr32 (+32: B)
  float ltB = cross_sum(lsB);
  __syncthreads();              // staging fully consumed
  if (kvh == 1) {
    float* cp = comb + ((size_t)qq * 64 + l) * 66;
#pragma unroll
    for (int r = 0; r < 16; r++) {
      cp[r] = oA0[r]; cp[16 + r] = oA1[r];
      cp[32 + r] = oB0[r]; cp[48 + r] = oB1[r];
    }
    cp[64] = ltA; cp[65] = ltB;
  }
  __syncthreads();
  if (kvh == 0) {
    const float* cp = comb + ((size_t)qq * 64 + l) * 66;
#pragma unroll
    for (int r = 0; r < 16; r++) {
      oA0[r] += cp[r]; oA1[r] += cp[16 + r];
      oB0[r] += cp[32 + r]; oB1[r] += cp[48 + r];
    }
    ltA += cp[64]; ltB += cp[65];
    u16* pob = (rng < 2) ? (pO01 + (size_t)(rng * 16 + bh) * 262144)
                         : (pO2 + (size_t)bh * 262144);
    if (hi == 0) {
      pL[rng * 65536 + bh * 4096 + q0 + qq * 64 + lr32]      = f2bf(ltA);
      pL[rng * 65536 + bh * 4096 + q0 + qq * 64 + 32 + lr32] = f2bf(ltB);
    }
#pragma unroll
    for (int r = 0; r < 16; r++) {
      int crow = (r & 3) + 8 * (r >> 2) + 4 * hi;
      size_t qrA = (size_t)(q0 + qq * 64 + crow);
      size_t qrB = qrA + 32;
      pob[qrA * 64 + lr32]      = f2bf(oA0[r]);
      pob[qrA * 64 + 32 + lr32] = f2bf(oA1[r]);
      pob[qrB * 64 + lr32]      = f2bf(oB0[r]);
      pob[qrB * 64 + 32 + lr32] = f2bf(oB1[r]);
    }
  }
}

// ---------------- kernel 5: combine 3 kv-range partials -> aout bf16 ---------
__global__ void k_reduce(const u16* __restrict__ pO01, const u16* __restrict__ pO2,
                         const u16* __restrict__ pL, u16* __restrict__ ob) {
  int o = blockIdx.x * 256 + threadIdx.x;      // 524288 octets of 8 elems
  int d8 = o & 7, q = (o >> 3) & 4095, bh = o >> 15;
  size_t pidx = ((size_t)bh * 4096 + q) * 64 + d8 * 8;
  u16x8 a = *(const u16x8*)(pO01 + pidx);
  u16x8 b = *(const u16x8*)(pO01 + 4194304 + pidx);
  u16x8 c = *(const u16x8*)(pO2 + pidx);
  float l0 = bf2f(pL[bh * 4096 + q]);
  float l1 = bf2f(pL[65536 + bh * 4096 + q]);
  float l2 = bf2f(pL[131072 + bh * 4096 + q]);
  float inv = __builtin_amdgcn_rcpf(l0 + l1 + l2);
  u16x8 r;
#pragma unroll
  for (int j = 0; j < 8; j++)
    r[j] = f2bf((bf2f(a[j]) + bf2f(b[j]) + bf2f(c[j])) * inv);
  int b_ = bh >> 2, h = bh & 3;
  *(u16x8*)(ob + ((size_t)b_ * 4096 + q) * 256 + h * 64 + d8 * 8) = r;
}

extern "C" void kernel_launch(void* const* d_in, const int* in_sizes, int n_in,
                              void* d_out, int out_size, void* d_ws, size_t ws_size,
                              hipStream_t stream) {
  const float* x   = (const float*)d_in[0];
  const float* ctx = (const float*)d_in[1];
  const float* Wq  = (const float*)d_in[2];
  const float* bq  = (const float*)d_in[3];
  const float* Wkv = (const float*)d_in[4];
  const float* bkv = (const float*)d_in[5];
  const float* Wp  = (const float*)d_in[6];
  const float* bp  = (const float*)d_in[7];

  char* ws = (char*)d_ws;
  u16* xb    = (u16*)(ws);
  u16* cb    = (u16*)(ws + 8388608);
  u16* wqT   = (u16*)(ws + 16777216);
  u16* wkvT  = (u16*)(ws + 16908288);
  u16* wpT   = (u16*)(ws + 17170432);
  u16* qbuf  = (u16*)(ws + 17301504);
  u16* kbuf  = (u16*)(ws + 25690112);
  u16* vtbuf = (u16*)(ws + 34078720);
  u16* aout  = (u16*)(ws + 42467328);
  // flash partials overlay dead buffers:
  //  pO01 (ranges 0,1; 16.78MB) over xb+cb (consumed by gemms before flash)
  //  pO2  (range 2; 8.39MB)     over d_out f32 region (rewritten by gemm<2>)
  //  pL   (393KB)               over wqT/wkvT/wpT (consumed before flash)
  u16* pO01 = (u16*)(ws);
  u16* pO2  = (u16*)(d_out);
  u16* pL   = (u16*)(ws + 16777216);
  float* out  = (float*)d_out;
  float* amap = out + 4194304;

  k_convert<<<8448, 256, 0, stream>>>(x, ctx, Wq, Wkv, Wp, xb, cb, wqT, wkvT, wpT, amap);
  k_gemm<0><<<dim3(128, 4), 256, 0, stream>>>(xb, wqT, bq, nullptr, qbuf, nullptr, nullptr);
  k_gemm<1><<<dim3(128, 8), 256, 0, stream>>>(cb, wkvT, bkv, nullptr, kbuf, vtbuf, nullptr);
  k_flash<<<dim3(32, 48), 256, 0, stream>>>(qbuf, kbuf, vtbuf, pO01, pO2, pL);
  k_reduce<<<2048, 256, 0, stream>>>(pO01, pO2, pL, aout);
  k_gemm<2><<<dim3(128, 4), 256, 0, stream>>>(aout, wpT, bp, x, nullptr, nullptr, out);
}

// Round 13
// 139.696 us; speedup vs baseline: 4.2330x; 4.2330x over previous
//
#include <hip/hip_runtime.h>
#include <stdint.h>

typedef unsigned short u16;
typedef short s16x8 __attribute__((ext_vector_type(8)));
typedef u16   u16x8 __attribute__((ext_vector_type(8)));
typedef float f32x4 __attribute__((ext_vector_type(4)));
typedef float f32x16 __attribute__((ext_vector_type(16)));

#define QSCALE 0.180336880111169f  /* 0.125 * log2(e) */

__device__ __forceinline__ u16 f2bf(float f) {
  union { float f; uint32_t u; } v; v.f = f;
  uint32_t r = (v.u + 0x7fffu + ((v.u >> 16) & 1u)) >> 16;
  return (u16)r;
}
__device__ __forceinline__ float bf2f(u16 x) {
  union { uint32_t u; float f; } v; v.u = (uint32_t)x << 16;
  return v.f;
}

__device__ __forceinline__ f32x4 mfma16(s16x8 a, s16x8 b, f32x4 c) {
  return __builtin_amdgcn_mfma_f32_16x16x32_bf16(a, b, c, 0, 0, 0);
}
__device__ __forceinline__ f32x16 mfma32(s16x8 a, s16x8 b, f32x16 c) {
  return __builtin_amdgcn_mfma_f32_32x32x16_bf16(a, b, c, 0, 0, 0);
}

__device__ __forceinline__ void gload16(const void* g, void* l) {
  __builtin_amdgcn_global_load_lds(
      (const __attribute__((address_space(1))) void*)g,
      (__attribute__((address_space(3))) void*)l, 16, 0, 0);
}

// read 8 contiguous bf16 from a [*][64]-u16 LDS tile with (row&7)<<4 XOR swizzle
__device__ __forceinline__ s16x8 ldsr(const u16* base, int row, int colb) {
  return *(const s16x8*)((const char*)base + row * 128 + (colb ^ ((row & 7) << 4)));
}

// pack two f32 -> bf16x2 word (lo = first)
__device__ __forceinline__ uint32_t cvtpk(float lo, float hi) {
  uint32_t r;
  asm("v_cvt_pk_bf16_f32 %0, %1, %2" : "=v"(r) : "v"(lo), "v"(hi));
  return r;
}
// v_permlane32_swap: a'[l<32]=a, a'[l>=32]=b[l-32]; b'[l<32]=a[l+32], b'[l>=32]=b
__device__ __forceinline__ void hswap(uint32_t& a, uint32_t& b) {
  asm("v_permlane32_swap_b32 %0, %1" : "+v"(a), "+v"(b));
}
__device__ __forceinline__ float cross_sum(float v) {
  float t = v, u = v;
  asm("v_permlane32_swap_b32 %0, %1" : "+v"(t), "+v"(u));
  return t + u;
}

// ------ kernel 1: convert x/ctx + weights to bf16, write attn_map=1 ----------
__global__ void k_convert(const float* __restrict__ x, const float* __restrict__ ctx,
                          const float* __restrict__ wq, const float* __restrict__ wkv,
                          const float* __restrict__ wp,
                          u16* __restrict__ xb, u16* __restrict__ cb,
                          u16* __restrict__ wqT, u16* __restrict__ wkvT,
                          u16* __restrict__ wpT, float* __restrict__ amap) {
  int tid = blockIdx.x * 256 + threadIdx.x;
  if (tid < 2097152) {            // x (4.2M) + ctx (4.2M), 4 floats each
    const float* src; u16* dst; int off;
    if (tid < 1048576) { src = x;   dst = xb; off = tid * 4; }
    else               { src = ctx; dst = cb; off = (tid - 1048576) * 4; }
    f32x4 v = *(const f32x4*)(src + off);
    u16* d = dst + off;
    d[0] = f2bf(v.x); d[1] = f2bf(v.y); d[2] = f2bf(v.z); d[3] = f2bf(v.w);
    if (tid < 16384) amap[tid] = 1.0f;   // sum_k softmax == 1 exactly
  } else {                        // weights: 262144 elems, transpose to [N][K]
    int t4 = (tid - 2097152) * 4;
#pragma unroll
    for (int j = 0; j < 4; j++) {
      int t = t4 + j;
      if (t < 65536) {
        int k = t >> 8, n = t & 255;
        wqT[n * 256 + k] = f2bf(wq[t]);
      } else if (t < 196608) {
        int t2 = t - 65536;
        int k = t2 >> 9, n = t2 & 511;
        wkvT[n * 256 + k] = f2bf(wkv[t2]);
      } else {
        int t2 = t - 196608;
        int k = t2 >> 8, n = t2 & 255;
        wpT[n * 256 + k] = f2bf(wp[t2]);
      }
    }
  }
}

// ---------------- kernel 2/3/6: MFMA GEMM  C[M,N] = A[M,256] @ Bt[N,256]^T ---
// EPI 0: q-proj (scale, scatter [B,H,L,hd]) ; EPI 1: kv-proj (k->[B,H,Lc,hd],
// v->tiled V^T [bh][kv/64][hd][64]) ; EPI 2: out-proj (+bias +x, fp32)
template<int EPI>
__global__ __launch_bounds__(256, 2) void k_gemm(
    const u16* __restrict__ A, const u16* __restrict__ Bt,
    const float* __restrict__ bias, const float* __restrict__ xres,
    u16* __restrict__ o16a, u16* __restrict__ o16b, float* __restrict__ o32) {
  __shared__ u16 Als[2][128 * 64];
  __shared__ u16 Bls[2][64 * 64];
  const int m0 = blockIdx.x * 128;
  const int n0 = blockIdx.y * 64;
  const int tid = threadIdx.x, w = tid >> 6, l = tid & 63;
  const int lr = l & 15, lg = l >> 4;
  const int wm = (w >> 1) * 64, wn = (w & 1) * 32;

  auto stage = [&](int buf, int k0) {
    const char* sa = (const char*)A;
#pragma unroll
    for (int i = 0; i < 4; i++) {
      int dbase = (w * 4 + i) * 1024;
      int d = dbase + l * 16;
      int row = d >> 7, colb = d & 127;
      gload16(sa + (size_t)(m0 + row) * 512 + k0 * 2 + (colb ^ ((row & 7) << 4)),
              (char*)Als[buf] + dbase);
    }
    const char* sb = (const char*)Bt;
#pragma unroll
    for (int i = 0; i < 2; i++) {
      int dbase = (w * 2 + i) * 1024;
      int d = dbase + l * 16;
      int row = d >> 7, colb = d & 127;
      gload16(sb + (size_t)(n0 + row) * 512 + k0 * 2 + (colb ^ ((row & 7) << 4)),
              (char*)Bls[buf] + dbase);
    }
  };

  f32x4 acc[4][2];
#pragma unroll
  for (int i = 0; i < 4; i++)
#pragma unroll
    for (int j = 0; j < 2; j++) acc[i][j] = (f32x4){0.f, 0.f, 0.f, 0.f};

  stage(0, 0);
  __syncthreads();
  int cur = 0;
  for (int ks = 0; ks < 4; ks++) {           // K = 256, BK = 64
    if (ks < 3) stage(cur ^ 1, (ks + 1) * 64);
    s16x8 a[4][2], b[2][2];
#pragma unroll
    for (int mt = 0; mt < 4; mt++)
#pragma unroll
      for (int kf = 0; kf < 2; kf++)
        a[mt][kf] = ldsr(Als[cur], wm + mt * 16 + lr, lg * 16 + kf * 64);
#pragma unroll
    for (int nt = 0; nt < 2; nt++)
#pragma unroll
      for (int kf = 0; kf < 2; kf++)
        b[nt][kf] = ldsr(Bls[cur], wn + nt * 16 + lr, lg * 16 + kf * 64);
#pragma unroll
    for (int mt = 0; mt < 4; mt++)
#pragma unroll
      for (int nt = 0; nt < 2; nt++) {
        acc[mt][nt] = mfma16(a[mt][0], b[nt][0], acc[mt][nt]);
        acc[mt][nt] = mfma16(a[mt][1], b[nt][1], acc[mt][nt]);
      }
    __syncthreads();
    cur ^= 1;
  }

#pragma unroll
  for (int mt = 0; mt < 4; mt++)
#pragma unroll
    for (int nt = 0; nt < 2; nt++)
#pragma unroll
      for (int r = 0; r < 4; r++) {
        int gm = m0 + wm + mt * 16 + lg * 4 + r;
        int gn = n0 + wn + nt * 16 + lr;
        float val = acc[mt][nt][r] + bias[gn];
        if constexpr (EPI == 0) {
          int b_ = gm >> 12, ql = gm & 4095, h = gn >> 6, dd = gn & 63;
          o16a[(((size_t)(b_ * 4 + h) * 4096 + ql) << 6) + dd] = f2bf(val * QSCALE);
        } else if constexpr (EPI == 1) {
          int b_ = gm >> 12, ql = gm & 4095;
          int s = gn >> 8, inner = gn & 255, h = inner >> 6, dd = inner & 63;
          if (s) {  // V^T tiled: [bh][ql/64][dd][ql%64]
            size_t addr = (((size_t)(b_ * 4 + h) * 64 + (ql >> 6)) * 64 + dd) * 64 + (ql & 63);
            o16b[addr] = f2bf(val);
          } else {  // K: [bh][kv][hd]
            size_t addr = (((size_t)(b_ * 4 + h) * 4096 + ql) << 6) + dd;
            o16a[addr] = f2bf(val);
          }
        } else {
          size_t idx = (size_t)gm * 256 + gn;
          o32[idx] = val + xres[idx];
        }
      }
}

// ---------------- kernel 4: flash attention (R9 geometry, 3-way kv ranges) ---
// Swapped-QK 32x32 MFMA, no-max softmax (S_log2 bounded ~[-1,1]; constant
// cancels). 1536 blocks x 4 waves, launch_bounds(256,2): compiler reproduces
// R9's ~96-VGPR clean allocation (NO spill); HW residency = min(grid 6/CU,
// LDS 4/CU, regs 3/CU) = 3 blocks/CU = 12 waves/CU (R9 was grid-limited to
// 2). Block = (bh, 128-q tile, kv range rng: tiles {0-20,21-41,42-63}). Wave
// geometry = R9: qq=w&1 64-q half, kvh=(w>>1)&1 32-kv half -> 8 b128 reads
// feed 16 MFMAs (1:2). Partials additive: in-block kvh fold via dead-staging
// LDS, bf16 partial O/lsum to global (3-way combined by k_reduce).
__global__ __launch_bounds__(256, 2) void k_flash(
    const u16* __restrict__ qb, const u16* __restrict__ kb,
    const u16* __restrict__ vtb, u16* __restrict__ pO01, u16* __restrict__ pO2,
    u16* __restrict__ pL) {
  __shared__ char smem[33792];
  u16* kls0 = (u16*)(smem);
  u16* kls1 = (u16*)(smem + 8192);
  u16* vls0 = (u16*)(smem + 16384);
  u16* vls1 = (u16*)(smem + 24576);
  float* comb = (float*)smem;               // overlays staging after loop
  const int id = blockIdx.y * 32 + blockIdx.x;      // 1536 blocks
  const int sw = (id & 7) * 192 + (id >> 3);        // XCD chunking (bijective)
  const int bh = sw / 96;                           // 2 bh per XCD chunk
  const int rem = sw - bh * 96;
  const int q0 = (rem / 3) * 128;
  const int rng = rem - (rem / 3) * 3;              // kv range 0..2
  const int t0 = rng * 21;
  const int nt = (rng == 2) ? 22 : 21;
  const int tid = threadIdx.x, w = tid >> 6, l = tid & 63;
  const int lr32 = l & 31, hi = l >> 5;
  const int qq = w & 1, kvh = (w >> 1) & 1;
  const char* kbase  = (const char*)(kb + (size_t)bh * 262144);
  const char* vtbase = (const char*)(vtb + (size_t)bh * 262144);

  // Q B-fragments, two qsets: qA: q = q0 + 64*qq + lr32 ; qB: +32
  s16x8 qfA[4], qfB[4];
  {
    const u16* qp = qb + ((size_t)bh * 4096 + q0 + qq * 64 + lr32) * 64 + hi * 8;
#pragma unroll
    for (int mm = 0; mm < 4; mm++) {
      qfA[mm] = *(const s16x8*)(qp + mm * 16);
      qfB[mm] = *(const s16x8*)(qp + 2048 + mm * 16);
    }
  }

  // stage K+V tile t (two contiguous 8KB tiles); 4 waves cover both
  auto stage = [&](u16* kbuf, u16* vbuf, int t) {
    const char* ks = kbase  + (size_t)t * 8192;
    const char* vs = vtbase + (size_t)t * 8192;
#pragma unroll
    for (int i = 0; i < 2; i++) {
      int d = w * 2048 + i * 1024 + l * 16;
      int row = d >> 7, colb = d & 127;
      int so = row * 128 + (colb ^ ((row & 7) << 4));
      gload16(ks + so, (char*)kbuf + d);
      gload16(vs + so, (char*)vbuf + d);
    }
  };

  f32x16 oA0, oA1, oB0, oB1;
  float lsA = 0.f, lsB = 0.f;
#pragma unroll
  for (int r = 0; r < 16; r++) { oA0[r] = 0.f; oA1[r] = 0.f; oB0[r] = 0.f; oB1[r] = 0.f; }

  auto compute = [&](const u16* kc, const u16* vc) {
    // K fragments for this wave's 32-kv half (4 reads, feed 8 QK MFMAs)
    s16x8 kf[4];
#pragma unroll
    for (int mm = 0; mm < 4; mm++)
      kf[mm] = ldsr(kc, kvh * 32 + lr32, mm * 32 + 16 * hi);
    f32x16 sA, sB;
#pragma unroll
    for (int r = 0; r < 16; r++) { sA[r] = 0.f; sB[r] = 0.f; }
    __builtin_amdgcn_s_setprio(1);
#pragma unroll
    for (int mm = 0; mm < 4; mm++) {
      sA = mfma32(kf[mm], qfA[mm], sA);
      sB = mfma32(kf[mm], qfB[mm], sB);
    }
    __builtin_amdgcn_s_setprio(0);
    // P = exp2(S); per-lane lsum
#pragma unroll
    for (int r = 0; r < 16; r++) {
      sA[r] = __builtin_amdgcn_exp2f(sA[r]);
      sB[r] = __builtin_amdgcn_exp2f(sB[r]);
    }
    float aA = 0.f, aB = 0.f;
#pragma unroll
    for (int r = 0; r < 16; r++) { aA += sA[r]; aB += sB[r]; }
    lsA += aA; lsB += aB;
    // V fragments (4 reads, feed 8 PV MFMAs across both qsets)
    s16x8 vf[2][2];
#pragma unroll
    for (int ks2 = 0; ks2 < 2; ks2++) {
      int vcol = kvh * 64 + 32 * ks2 + 16 * hi;
      vf[ks2][0] = ldsr(vc, lr32,      vcol);
      vf[ks2][1] = ldsr(vc, 32 + lr32, vcol);
    }
#pragma unroll
    for (int ks2 = 0; ks2 < 2; ks2++) {
      uint32_t A0 = cvtpk(sA[8 * ks2 + 0], sA[8 * ks2 + 1]);
      uint32_t A1 = cvtpk(sA[8 * ks2 + 2], sA[8 * ks2 + 3]);
      uint32_t B0 = cvtpk(sA[8 * ks2 + 4], sA[8 * ks2 + 5]);
      uint32_t B1 = cvtpk(sA[8 * ks2 + 6], sA[8 * ks2 + 7]);
      hswap(A0, B0);
      hswap(A1, B1);
      union { uint32_t wv[4]; s16x8 h; } pa;
      pa.wv[0] = A0; pa.wv[1] = A1; pa.wv[2] = B0; pa.wv[3] = B1;
      uint32_t C0 = cvtpk(sB[8 * ks2 + 0], sB[8 * ks2 + 1]);
      uint32_t C1 = cvtpk(sB[8 * ks2 + 2], sB[8 * ks2 + 3]);
      uint32_t D0 = cvtpk(sB[8 * ks2 + 4], sB[8 * ks2 + 5]);
      uint32_t D1 = cvtpk(sB[8 * ks2 + 6], sB[8 * ks2 + 7]);
      hswap(C0, D0);
      hswap(C1, D1);
      union { uint32_t wv[4]; s16x8 h; } pb;
      pb.wv[0] = C0; pb.wv[1] = C1; pb.wv[2] = D0; pb.wv[3] = D1;
      __builtin_amdgcn_s_setprio(1);
      oA0 = mfma32(pa.h, vf[ks2][0], oA0);
      oA1 = mfma32(pa.h, vf[ks2][1], oA1);
      oB0 = mfma32(pb.h, vf[ks2][0], oB0);
      oB1 = mfma32(pb.h, vf[ks2][1], oB1);
      __builtin_amdgcn_s_setprio(0);
    }
  };

  stage(kls0, vls0, t0);
  int i = 0;
  while (true) {
    asm volatile("s_waitcnt vmcnt(0)" ::: "memory");
    __builtin_amdgcn_s_barrier();
    asm volatile("" ::: "memory");
    if (i + 1 < nt) stage(kls1, vls1, t0 + i + 1);
    compute(kls0, vls0);
    if (++i == nt) break;
    asm volatile("s_waitcnt vmcnt(0)" ::: "memory");
    __builtin_amdgcn_s_barrier();
    asm volatile("" ::: "memory");
    if (i + 1 < nt) stage(kls0, vls0, t0 + i + 1);
    compute(kls1, vls1);
    if (++i == nt) break;
  }

  // ---- fold wave-kvh (additive partials), write bf16 partials -------------
  float ltA = cross_sum(lsA);   // range kv sum for q = q0+64qq+lr32 (+32: B)
  float ltB = cross_sum(lsB);
  __syncthreads();              // staging fully consumed
  if (kvh == 1) {
    float* cp = comb + ((size_t)qq * 64 + l) * 66;
#pragma unroll
    for (int r = 0; r < 16; r++) {
      cp[r] = oA0[r]; cp[16 + r] = oA1[r];
      cp[32 + r] = oB0[r]; cp[48 + r] = oB1[r];
    }
    cp[64] = ltA; cp[65] = ltB;
  }
  __syncthreads();
  if (kvh == 0) {
    const float* cp = comb + ((size_t)qq * 64 + l) * 66;
#pragma unroll
    for (int r = 0; r < 16; r++) {
      oA0[r] += cp[r]; oA1[r] += cp[16 + r];
      oB0[r] += cp[32 + r]; oB1[r] += cp[48 + r];
    }
    ltA += cp[64]; ltB += cp[65];
    u16* pob = (rng < 2) ? (pO01 + (size_t)(rng * 16 + bh) * 262144)
                         : (pO2 + (size_t)bh * 262144);
    if (hi == 0) {
      pL[rng * 65536 + bh * 4096 + q0 + qq * 64 + lr32]      = f2bf(ltA);
      pL[rng * 65536 + bh * 4096 + q0 + qq * 64 + 32 + lr32] = f2bf(ltB);
    }
#pragma unroll
    for (int r = 0; r < 16; r++) {
      int crow = (r & 3) + 8 * (r >> 2) + 4 * hi;
      size_t qrA = (size_t)(q0 + qq * 64 + crow);
      size_t qrB = qrA + 32;
      pob[qrA * 64 + lr32]      = f2bf(oA0[r]);
      pob[qrA * 64 + 32 + lr32] = f2bf(oA1[r]);
      pob[qrB * 64 + lr32]      = f2bf(oB0[r]);
      pob[qrB * 64 + 32 + lr32] = f2bf(oB1[r]);
    }
  }
}

// ---------------- kernel 5: combine 3 kv-range partials -> aout bf16 ---------
__global__ void k_reduce(const u16* __restrict__ pO01, const u16* __restrict__ pO2,
                         const u16* __restrict__ pL, u16* __restrict__ ob) {
  int o = blockIdx.x * 256 + threadIdx.x;      // 524288 octets of 8 elems
  int d8 = o & 7, q = (o >> 3) & 4095, bh = o >> 15;
  size_t pidx = ((size_t)bh * 4096 + q) * 64 + d8 * 8;
  u16x8 a = *(const u16x8*)(pO01 + pidx);
  u16x8 b = *(const u16x8*)(pO01 + 4194304 + pidx);
  u16x8 c = *(const u16x8*)(pO2 + pidx);
  float l0 = bf2f(pL[bh * 4096 + q]);
  float l1 = bf2f(pL[65536 + bh * 4096 + q]);
  float l2 = bf2f(pL[131072 + bh * 4096 + q]);
  float inv = __builtin_amdgcn_rcpf(l0 + l1 + l2);
  u16x8 r;
#pragma unroll
  for (int j = 0; j < 8; j++)
    r[j] = f2bf((bf2f(a[j]) + bf2f(b[j]) + bf2f(c[j])) * inv);
  int b_ = bh >> 2, h = bh & 3;
  *(u16x8*)(ob + ((size_t)b_ * 4096 + q) * 256 + h * 64 + d8 * 8) = r;
}

extern "C" void kernel_launch(void* const* d_in, const int* in_sizes, int n_in,
                              void* d_out, int out_size, void* d_ws, size_t ws_size,
                              hipStream_t stream) {
  const float* x   = (const float*)d_in[0];
  const float* ctx = (const float*)d_in[1];
  const float* Wq  = (const float*)d_in[2];
  const float* bq  = (const float*)d_in[3];
  const float* Wkv = (const float*)d_in[4];
  const float* bkv = (const float*)d_in[5];
  const float* Wp  = (const float*)d_in[6];
  const float* bp  = (const float*)d_in[7];

  char* ws = (char*)d_ws;
  u16* xb    = (u16*)(ws);
  u16* cb    = (u16*)(ws + 8388608);
  u16* wqT   = (u16*)(ws + 16777216);
  u16* wkvT  = (u16*)(ws + 16908288);
  u16* wpT   = (u16*)(ws + 17170432);
  u16* qbuf  = (u16*)(ws + 17301504);
  u16* kbuf  = (u16*)(ws + 25690112);
  u16* vtbuf = (u16*)(ws + 34078720);
  u16* aout  = (u16*)(ws + 42467328);
  // flash partials overlay dead buffers:
  //  pO01 (ranges 0,1; 16.78MB) over xb+cb (consumed by gemms before flash)
  //  pO2  (range 2; 8.39MB)     over d_out f32 region (rewritten by gemm<2>)
  //  pL   (393KB)               over wqT/wkvT/wpT (consumed before flash)
  u16* pO01 = (u16*)(ws);
  u16* pO2  = (u16*)(d_out);
  u16* pL   = (u16*)(ws + 16777216);
  float* out  = (float*)d_out;
  float* amap = out + 4194304;

  k_convert<<<8448, 256, 0, stream>>>(x, ctx, Wq, Wkv, Wp, xb, cb, wqT, wkvT, wpT, amap);
  k_gemm<0><<<dim3(128, 4), 256, 0, stream>>>(xb, wqT, bq, nullptr, qbuf, nullptr, nullptr);
  k_gemm<1><<<dim3(128, 8), 256, 0, stream>>>(cb, wkvT, bkv, nullptr, kbuf, vtbuf, nullptr);
  k_flash<<<dim3(32, 48), 256, 0, stream>>>(qbuf, kbuf, vtbuf, pO01, pO2, pL);
  k_reduce<<<2048, 256, 0, stream>>>(pO01, pO2, pL, aout);
  k_gemm<2><<<dim3(128, 4), 256, 0, stream>>>(aout, wpT, bp, x, nullptr, nullptr, out);
}

// Round 14
// 128.513 us; speedup vs baseline: 4.6013x; 1.0870x over previous
//
#include <hip/hip_runtime.h>
#include <stdint.h>

typedef unsigned short u16;
typedef short s16x8 __attribute__((ext_vector_type(8)));
typedef u16   u16x8 __attribute__((ext_vector_type(8)));
typedef float f32x4 __attribute__((ext_vector_type(4)));
typedef float f32x16 __attribute__((ext_vector_type(16)));

#define QSCALE 0.180336880111169f  /* 0.125 * log2(e) */

__device__ __forceinline__ u16 f2bf(float f) {
  union { float f; uint32_t u; } v; v.f = f;
  uint32_t r = (v.u + 0x7fffu + ((v.u >> 16) & 1u)) >> 16;
  return (u16)r;
}

__device__ __forceinline__ f32x4 mfma16(s16x8 a, s16x8 b, f32x4 c) {
  return __builtin_amdgcn_mfma_f32_16x16x32_bf16(a, b, c, 0, 0, 0);
}
__device__ __forceinline__ f32x16 mfma32(s16x8 a, s16x8 b, f32x16 c) {
  return __builtin_amdgcn_mfma_f32_32x32x16_bf16(a, b, c, 0, 0, 0);
}

__device__ __forceinline__ void gload16(const void* g, void* l) {
  __builtin_amdgcn_global_load_lds(
      (const __attribute__((address_space(1))) void*)g,
      (__attribute__((address_space(3))) void*)l, 16, 0, 0);
}

// read 8 contiguous bf16 from a [*][64]-u16 LDS tile with (row&7)<<4 XOR swizzle
__device__ __forceinline__ s16x8 ldsr(const u16* base, int row, int colb) {
  return *(const s16x8*)((const char*)base + row * 128 + (colb ^ ((row & 7) << 4)));
}

// pack two f32 -> bf16x2 word (lo = first)
__device__ __forceinline__ uint32_t cvtpk(float lo, float hi) {
  uint32_t r;
  asm("v_cvt_pk_bf16_f32 %0, %1, %2" : "=v"(r) : "v"(lo), "v"(hi));
  return r;
}
// v_permlane32_swap: a'[l<32]=a, a'[l>=32]=b[l-32]; b'[l<32]=a[l+32], b'[l>=32]=b
__device__ __forceinline__ void hswap(uint32_t& a, uint32_t& b) {
  asm("v_permlane32_swap_b32 %0, %1" : "+v"(a), "+v"(b));
}

// ------ kernel 1: convert x/ctx + weights to bf16, write attn_map=1 ----------
__global__ void k_convert(const float* __restrict__ x, const float* __restrict__ ctx,
                          const float* __restrict__ wq, const float* __restrict__ wkv,
                          const float* __restrict__ wp,
                          u16* __restrict__ xb, u16* __restrict__ cb,
                          u16* __restrict__ wqT, u16* __restrict__ wkvT,
                          u16* __restrict__ wpT, float* __restrict__ amap) {
  int tid = blockIdx.x * 256 + threadIdx.x;
  if (tid < 2097152) {            // x (4.2M) + ctx (4.2M), 4 floats each
    const float* src; u16* dst; int off;
    if (tid < 1048576) { src = x;   dst = xb; off = tid * 4; }
    else               { src = ctx; dst = cb; off = (tid - 1048576) * 4; }
    f32x4 v = *(const f32x4*)(src + off);
    u16* d = dst + off;
    d[0] = f2bf(v.x); d[1] = f2bf(v.y); d[2] = f2bf(v.z); d[3] = f2bf(v.w);
    if (tid < 16384) amap[tid] = 1.0f;   // sum_k softmax == 1 exactly
  } else {                        // weights: 262144 elems, transpose to [N][K]
    int t4 = (tid - 2097152) * 4;
#pragma unroll
    for (int j = 0; j < 4; j++) {
      int t = t4 + j;
      if (t < 65536) {
        int k = t >> 8, n = t & 255;
        wqT[n * 256 + k] = f2bf(wq[t]);
      } else if (t < 196608) {
        int t2 = t - 65536;
        int k = t2 >> 9, n = t2 & 511;
        wkvT[n * 256 + k] = f2bf(wkv[t2]);
      } else {
        int t2 = t - 196608;
        int k = t2 >> 8, n = t2 & 255;
        wpT[n * 256 + k] = f2bf(wp[t2]);
      }
    }
  }
}

// ---------------- kernel 2/3/5: MFMA GEMM  C[M,N] = A[M,256] @ Bt[N,256]^T ---
// EPI 0: q-proj (scale, scatter [B,H,L,hd]) ; EPI 1: kv-proj (k->[B,H,Lc,hd],
// v->tiled V^T [bh][kv/64][hd][64]) ; EPI 2: out-proj (+bias +x, fp32)
template<int EPI>
__global__ __launch_bounds__(256, 2) void k_gemm(
    const u16* __restrict__ A, const u16* __restrict__ Bt,
    const float* __restrict__ bias, const float* __restrict__ xres,
    u16* __restrict__ o16a, u16* __restrict__ o16b, float* __restrict__ o32) {
  __shared__ u16 Als[2][128 * 64];
  __shared__ u16 Bls[2][64 * 64];
  const int m0 = blockIdx.x * 128;
  const int n0 = blockIdx.y * 64;
  const int tid = threadIdx.x, w = tid >> 6, l = tid & 63;
  const int lr = l & 15, lg = l >> 4;
  const int wm = (w >> 1) * 64, wn = (w & 1) * 32;

  auto stage = [&](int buf, int k0) {
    const char* sa = (const char*)A;
#pragma unroll
    for (int i = 0; i < 4; i++) {
      int dbase = (w * 4 + i) * 1024;
      int d = dbase + l * 16;
      int row = d >> 7, colb = d & 127;
      gload16(sa + (size_t)(m0 + row) * 512 + k0 * 2 + (colb ^ ((row & 7) << 4)),
              (char*)Als[buf] + dbase);
    }
    const char* sb = (const char*)Bt;
#pragma unroll
    for (int i = 0; i < 2; i++) {
      int dbase = (w * 2 + i) * 1024;
      int d = dbase + l * 16;
      int row = d >> 7, colb = d & 127;
      gload16(sb + (size_t)(n0 + row) * 512 + k0 * 2 + (colb ^ ((row & 7) << 4)),
              (char*)Bls[buf] + dbase);
    }
  };

  f32x4 acc[4][2];
#pragma unroll
  for (int i = 0; i < 4; i++)
#pragma unroll
    for (int j = 0; j < 2; j++) acc[i][j] = (f32x4){0.f, 0.f, 0.f, 0.f};

  stage(0, 0);
  __syncthreads();
  int cur = 0;
  for (int ks = 0; ks < 4; ks++) {           // K = 256, BK = 64
    if (ks < 3) stage(cur ^ 1, (ks + 1) * 64);
    s16x8 a[4][2], b[2][2];
#pragma unroll
    for (int mt = 0; mt < 4; mt++)
#pragma unroll
      for (int kf = 0; kf < 2; kf++)
        a[mt][kf] = ldsr(Als[cur], wm + mt * 16 + lr, lg * 16 + kf * 64);
#pragma unroll
    for (int nt = 0; nt < 2; nt++)
#pragma unroll
      for (int kf = 0; kf < 2; kf++)
        b[nt][kf] = ldsr(Bls[cur], wn + nt * 16 + lr, lg * 16 + kf * 64);
#pragma unroll
    for (int mt = 0; mt < 4; mt++)
#pragma unroll
      for (int nt = 0; nt < 2; nt++) {
        acc[mt][nt] = mfma16(a[mt][0], b[nt][0], acc[mt][nt]);
        acc[mt][nt] = mfma16(a[mt][1], b[nt][1], acc[mt][nt]);
      }
    __syncthreads();
    cur ^= 1;
  }

#pragma unroll
  for (int mt = 0; mt < 4; mt++)
#pragma unroll
    for (int nt = 0; nt < 2; nt++)
#pragma unroll
      for (int r = 0; r < 4; r++) {
        int gm = m0 + wm + mt * 16 + lg * 4 + r;
        int gn = n0 + wn + nt * 16 + lr;
        float val = acc[mt][nt][r] + bias[gn];
        if constexpr (EPI == 0) {
          int b_ = gm >> 12, ql = gm & 4095, h = gn >> 6, dd = gn & 63;
          o16a[(((size_t)(b_ * 4 + h) * 4096 + ql) << 6) + dd] = f2bf(val * QSCALE);
        } else if constexpr (EPI == 1) {
          int b_ = gm >> 12, ql = gm & 4095;
          int s = gn >> 8, inner = gn & 255, h = inner >> 6, dd = inner & 63;
          if (s) {  // V^T tiled: [bh][ql/64][dd][ql%64]
            size_t addr = (((size_t)(b_ * 4 + h) * 64 + (ql >> 6)) * 64 + dd) * 64 + (ql & 63);
            o16b[addr] = f2bf(val);
          } else {  // K: [bh][kv][hd]
            size_t addr = (((size_t)(b_ * 4 + h) * 4096 + ql) << 6) + dd;
            o16a[addr] = f2bf(val);
          }
        } else {
          size_t idx = (size_t)gm * 256 + gn;
          o32[idx] = val + xres[idx];
        }
      }
}

// ---------------- kernel 4: flash attention (R9 geometry, pair-sync) ---------
// Swapped-QK 32x32 MFMA, no-max softmax (S_log2 bounded ~[-1,1]; constant
// cancels). 512 blocks x 4 waves (proven R9 residency: 2 blk/CU, reg-capped).
// qq=w&1 64-q half, kvh=(w>>1)&1 32-kv half -> 8 b128 reads feed 20 MFMAs.
// NEW vs R9: (a) 4 LDS buffers, 2 tiles staged/computed per barrier ->
// barrier+vmcnt events halved, compiler can overlap QK(t+1) with PV(t);
// (b) lsum via ones-B MFMA (ls rows match O rows -> epilogue fully in-lane,
// no cross_sum/broadcast; removes 32 VALU adds/tile from the serial chain).
__global__ __launch_bounds__(256, 2) void k_flash(
    const u16* __restrict__ qb, const u16* __restrict__ kb,
    const u16* __restrict__ vtb, u16* __restrict__ ob) {
  __shared__ char smem[65536];   // 4x (K 8KB) + 4x (V 8KB); comb overlays
  float* comb = (float*)smem;
  const int id = blockIdx.y * 32 + blockIdx.x;      // 512 blocks
  const int sw = (id & 7) * 64 + (id >> 3);         // XCD chunking (bijective)
  const int bh = sw >> 5;
  const int q0 = (sw & 31) * 128;
  const int tid = threadIdx.x, w = tid >> 6, l = tid & 63;
  const int lr32 = l & 31, hi = l >> 5;
  const int qq = w & 1, kvh = (w >> 1) & 1;
  const char* kbase  = (const char*)(kb + (size_t)bh * 262144);
  const char* vtbase = (const char*)(vtb + (size_t)bh * 262144);

  // Q B-fragments, two qsets: qA: q = q0 + 64*qq + lr32 ; qB: +32
  s16x8 qfA[4], qfB[4];
  {
    const u16* qp = qb + ((size_t)bh * 4096 + q0 + qq * 64 + lr32) * 64 + hi * 8;
#pragma unroll
    for (int mm = 0; mm < 4; mm++) {
      qfA[mm] = *(const s16x8*)(qp + mm * 16);
      qfB[mm] = *(const s16x8*)(qp + 2048 + mm * 16);
    }
  }
  union { u16 u[8]; s16x8 h; } onesu;
#pragma unroll
  for (int j = 0; j < 8; j++) onesu.u[j] = 0x3f80;  // bf16 1.0

  // stage K+V tile t into buffer buf (0..3); 4 waves cover both 8KB tiles
  auto stage = [&](int buf, int t) {
    const char* ks = kbase  + (size_t)t * 8192;
    const char* vs = vtbase + (size_t)t * 8192;
    char* kd = smem + buf * 8192;
    char* vd = smem + 32768 + buf * 8192;
#pragma unroll
    for (int i = 0; i < 2; i++) {
      int d = w * 2048 + i * 1024 + l * 16;
      int row = d >> 7, colb = d & 127;
      int so = row * 128 + (colb ^ ((row & 7) << 4));
      gload16(ks + so, kd + d);
      gload16(vs + so, vd + d);
    }
  };

  f32x16 oA0, oA1, oB0, oB1, lsA, lsB;
#pragma unroll
  for (int r = 0; r < 16; r++) {
    oA0[r] = 0.f; oA1[r] = 0.f; oB0[r] = 0.f; oB1[r] = 0.f;
    lsA[r] = 0.f; lsB[r] = 0.f;
  }

  auto compute = [&](int buf) {
    const u16* kc = (const u16*)(smem + buf * 8192);
    const u16* vc = (const u16*)(smem + 32768 + buf * 8192);
    // K fragments for this wave's 32-kv half (4 reads, feed 8 QK MFMAs)
    s16x8 kf[4];
#pragma unroll
    for (int mm = 0; mm < 4; mm++)
      kf[mm] = ldsr(kc, kvh * 32 + lr32, mm * 32 + 16 * hi);
    f32x16 sA, sB;
#pragma unroll
    for (int r = 0; r < 16; r++) { sA[r] = 0.f; sB[r] = 0.f; }
    __builtin_amdgcn_s_setprio(1);
#pragma unroll
    for (int mm = 0; mm < 4; mm++) {
      sA = mfma32(kf[mm], qfA[mm], sA);
      sB = mfma32(kf[mm], qfB[mm], sB);
    }
    __builtin_amdgcn_s_setprio(0);
    // P = exp2(S)  (no max; constant cancels in normalization)
#pragma unroll
    for (int r = 0; r < 16; r++) {
      sA[r] = __builtin_amdgcn_exp2f(sA[r]);
      sB[r] = __builtin_amdgcn_exp2f(sB[r]);
    }
    // V fragments (4 reads, feed 8 PV MFMAs across both qsets)
    s16x8 vf[2][2];
#pragma unroll
    for (int ks2 = 0; ks2 < 2; ks2++) {
      int vcol = kvh * 64 + 32 * ks2 + 16 * hi;
      vf[ks2][0] = ldsr(vc, lr32,      vcol);
      vf[ks2][1] = ldsr(vc, 32 + lr32, vcol);
    }
#pragma unroll
    for (int ks2 = 0; ks2 < 2; ks2++) {
      uint32_t A0 = cvtpk(sA[8 * ks2 + 0], sA[8 * ks2 + 1]);
      uint32_t A1 = cvtpk(sA[8 * ks2 + 2], sA[8 * ks2 + 3]);
      uint32_t B0 = cvtpk(sA[8 * ks2 + 4], sA[8 * ks2 + 5]);
      uint32_t B1 = cvtpk(sA[8 * ks2 + 6], sA[8 * ks2 + 7]);
      hswap(A0, B0);
      hswap(A1, B1);
      union { uint32_t wv[4]; s16x8 h; } pa;
      pa.wv[0] = A0; pa.wv[1] = A1; pa.wv[2] = B0; pa.wv[3] = B1;
      uint32_t C0 = cvtpk(sB[8 * ks2 + 0], sB[8 * ks2 + 1]);
      uint32_t C1 = cvtpk(sB[8 * ks2 + 2], sB[8 * ks2 + 3]);
      uint32_t D0 = cvtpk(sB[8 * ks2 + 4], sB[8 * ks2 + 5]);
      uint32_t D1 = cvtpk(sB[8 * ks2 + 6], sB[8 * ks2 + 7]);
      hswap(C0, D0);
      hswap(C1, D1);
      union { uint32_t wv[4]; s16x8 h; } pb;
      pb.wv[0] = C0; pb.wv[1] = C1; pb.wv[2] = D0; pb.wv[3] = D1;
      __builtin_amdgcn_s_setprio(1);
      oA0 = mfma32(pa.h, vf[ks2][0], oA0);
      oA1 = mfma32(pa.h, vf[ks2][1], oA1);
      lsA = mfma32(pa.h, onesu.h, lsA);
      oB0 = mfma32(pb.h, vf[ks2][0], oB0);
      oB1 = mfma32(pb.h, vf[ks2][1], oB1);
      lsB = mfma32(pb.h, onesu.h, lsB);
      __builtin_amdgcn_s_setprio(0);
    }
  };

  // prologue: tiles 0,1 into buffers 0,1
  stage(0, 0); stage(1, 1);
#pragma unroll 1
  for (int tt = 0; tt < 16; tt++) {
    const int t = tt * 4;
    // phase A: compute bufs 0,1 (tiles t,t+1); stage bufs 2,3 (t+2,t+3)
    asm volatile("s_waitcnt vmcnt(0)" ::: "memory");
    __builtin_amdgcn_s_barrier();
    asm volatile("" ::: "memory");
    if (t + 2 < 64) { stage(2, t + 2); stage(3, t + 3); }
    compute(0);
    compute(1);
    // phase B: compute bufs 2,3 (t+2,t+3); stage bufs 0,1 (t+4,t+5)
    asm volatile("s_waitcnt vmcnt(0)" ::: "memory");
    __builtin_amdgcn_s_barrier();
    asm volatile("" ::: "memory");
    if (t + 4 < 64) { stage(0, t + 4); stage(1, t + 5); }
    compute(2);
    compute(3);
  }

  // ---- fold kv-halves (additive partials; ls rows match O rows) -----------
  __syncthreads();              // staging fully consumed
  if (kvh == 1) {
    float* cp = comb + ((size_t)qq * 64 + l) * 97;   // stride 97: conflict-free
#pragma unroll
    for (int r = 0; r < 16; r++) {
      cp[r] = oA0[r];      cp[16 + r] = oA1[r];
      cp[32 + r] = oB0[r]; cp[48 + r] = oB1[r];
      cp[64 + r] = lsA[r]; cp[80 + r] = lsB[r];
    }
  }
  __syncthreads();
  if (kvh == 0) {
    const float* cp = comb + ((size_t)qq * 64 + l) * 97;
#pragma unroll
    for (int r = 0; r < 16; r++) {
      oA0[r] += cp[r];      oA1[r] += cp[16 + r];
      oB0[r] += cp[32 + r]; oB1[r] += cp[48 + r];
      lsA[r] += cp[64 + r]; lsB[r] += cp[80 + r];
    }
    const int b_ = bh >> 2, h = bh & 3;
    u16* obase = ob + (size_t)b_ * 4096 * 256 + h * 64;
#pragma unroll
    for (int r = 0; r < 16; r++) {
      int crow = (r & 3) + 8 * (r >> 2) + 4 * hi;
      float invA = __builtin_amdgcn_rcpf(lsA[r]);
      float invB = __builtin_amdgcn_rcpf(lsB[r]);
      size_t qrA = (size_t)(q0 + qq * 64 + crow);
      size_t qrB = qrA + 32;
      obase[qrA * 256 + lr32]      = f2bf(oA0[r] * invA);
      obase[qrA * 256 + 32 + lr32] = f2bf(oA1[r] * invA);
      obase[qrB * 256 + lr32]      = f2bf(oB0[r] * invB);
      obase[qrB * 256 + 32 + lr32] = f2bf(oB1[r] * invB);
    }
  }
}

extern "C" void kernel_launch(void* const* d_in, const int* in_sizes, int n_in,
                              void* d_out, int out_size, void* d_ws, size_t ws_size,
                              hipStream_t stream) {
  const float* x   = (const float*)d_in[0];
  const float* ctx = (const float*)d_in[1];
  const float* Wq  = (const float*)d_in[2];
  const float* bq  = (const float*)d_in[3];
  const float* Wkv = (const float*)d_in[4];
  const float* bkv = (const float*)d_in[5];
  const float* Wp  = (const float*)d_in[6];
  const float* bp  = (const float*)d_in[7];

  char* ws = (char*)d_ws;
  u16* xb    = (u16*)(ws);
  u16* cb    = (u16*)(ws + 8388608);
  u16* wqT   = (u16*)(ws + 16777216);
  u16* wkvT  = (u16*)(ws + 16908288);
  u16* wpT   = (u16*)(ws + 17170432);
  u16* qbuf  = (u16*)(ws + 17301504);
  u16* kbuf  = (u16*)(ws + 25690112);
  u16* vtbuf = (u16*)(ws + 34078720);
  u16* aout  = (u16*)(ws + 42467328);
  float* out  = (float*)d_out;
  float* amap = out + 4194304;

  k_convert<<<8448, 256, 0, stream>>>(x, ctx, Wq, Wkv, Wp, xb, cb, wqT, wkvT, wpT, amap);
  k_gemm<0><<<dim3(128, 4), 256, 0, stream>>>(xb, wqT, bq, nullptr, qbuf, nullptr, nullptr);
  k_gemm<1><<<dim3(128, 8), 256, 0, stream>>>(cb, wkvT, bkv, nullptr, kbuf, vtbuf, nullptr);
  k_flash<<<dim3(32, 16), 256, 0, stream>>>(qbuf, kbuf, vtbuf, aout);
  k_gemm<2><<<dim3(128, 4), 256, 0, stream>>>(aout, wpT, bp, x, nullptr, nullptr, out);
}